// Round 5
// baseline (1606.440 us; speedup 1.0000x reference)
//
#include <hip/hip_runtime.h>
#include <cstdint>
#include <cstddef>

// ---------------------------------------------------------------------------
// BurnoutGAT: 2-layer GAT (PyG-style, self-loops, segment softmax) + BN + ELU
// N=50000 nodes, E=800000 edges, IN=13, L1: heads=4 ch=64 concat,
// BN+ELU, L2: heads=2 ch=32 mean, ELU, linear 32->1.
// ---------------------------------------------------------------------------

#define NEG_SLOPE 0.2f
#define BN_EPS 1e-5f

// monotonic float<->uint mapping for atomicMax on floats
__device__ __forceinline__ unsigned fmapf(float f) {
  unsigned u = __float_as_uint(f);
  return (u & 0x80000000u) ? ~u : (u | 0x80000000u);
}
__device__ __forceinline__ float funmapf(unsigned u) {
  return (u & 0x80000000u) ? __uint_as_float(u ^ 0x80000000u)
                           : __uint_as_float(~u);
}

// K1: h1 = x @ W1  [N,256]; a_src1/a_dst1 [N,4] (per-head dot with att vecs)
__global__ __launch_bounds__(256) void k1_linear1(
    const float* __restrict__ x, const float* __restrict__ W1,
    const float* __restrict__ att_src1, const float* __restrict__ att_dst1,
    float* __restrict__ h1, float* __restrict__ a_src1, float* __restrict__ a_dst1,
    int N) {
  __shared__ float xs[13];
  int n = blockIdx.x;
  int f = threadIdx.x;
  if (f < 13) xs[f] = x[(size_t)n * 13 + f];
  __syncthreads();
  float acc = 0.f;
#pragma unroll
  for (int k = 0; k < 13; ++k) acc = fmaf(xs[k], W1[k * 256 + f], acc);
  h1[(size_t)n * 256 + f] = acc;
  int lane = f & 63, wv = f >> 6;  // wave wv == head wv (64 ch per head)
  float ps = acc * att_src1[f];
  float pd = acc * att_dst1[f];
#pragma unroll
  for (int m = 32; m; m >>= 1) {
    ps += __shfl_xor(ps, m);
    pd += __shfl_xor(pd, m);
  }
  if (lane == 0) {
    a_src1[(size_t)n * 4 + wv] = ps;
    a_dst1[(size_t)n * 4 + wv] = pd;
  }
}

// K2 (layer1): alpha = leaky_relu(a_src[s]+a_dst[d]); store; segment max via atomicMax
__global__ void k2_alpha1(const float* __restrict__ a_src, const float* __restrict__ a_dst,
                          const int* __restrict__ src, const int* __restrict__ dst,
                          float* __restrict__ alpha, unsigned* __restrict__ amax,
                          int E, int Et) {
  int e = blockIdx.x * blockDim.x + threadIdx.x;
  if (e >= Et) return;
  int s, d;
  if (e < E) { s = src[e]; d = dst[e]; } else { s = d = e - E; }
#pragma unroll
  for (int hd = 0; hd < 4; ++hd) {
    float a = a_src[(size_t)s * 4 + hd] + a_dst[(size_t)d * 4 + hd];
    a = a >= 0.f ? a : NEG_SLOPE * a;
    alpha[(size_t)e * 4 + hd] = a;
    atomicMax(&amax[(size_t)d * 4 + hd], fmapf(a));
  }
}

// K3 (layer1): e = exp(alpha - amax[d]); store back; denom[d] += e
__global__ void k3_expsum1(const int* __restrict__ dst,
                           float* __restrict__ alpha, const unsigned* __restrict__ amax,
                           float* __restrict__ denom, int E, int Et) {
  int e = blockIdx.x * blockDim.x + threadIdx.x;
  if (e >= Et) return;
  int d = (e < E) ? dst[e] : (e - E);
#pragma unroll
  for (int hd = 0; hd < 4; ++hd) {
    float m = funmapf(amax[(size_t)d * 4 + hd]);
    float ev = __expf(alpha[(size_t)e * 4 + hd] - m);
    alpha[(size_t)e * 4 + hd] = ev;
    unsafeAtomicAdd(&denom[(size_t)d * 4 + hd], ev);
  }
}

// K4 (layer1): o1[d] += h1[s] * (alpha/denom[d]); one wave per edge, 256 feats
__global__ __launch_bounds__(256) void k4_aggregate1(
    const float* __restrict__ h1, const float* __restrict__ alpha,
    const float* __restrict__ denom,
    const int* __restrict__ src, const int* __restrict__ dst,
    float* __restrict__ o1, int E, int Et) {
  int gid = blockIdx.x * blockDim.x + threadIdx.x;
  int e = gid >> 6;
  if (e >= Et) return;
  int lane = threadIdx.x & 63;
  int s, d;
  if (e < E) { s = src[e]; d = dst[e]; } else { s = d = e - E; }
  float w[4];
#pragma unroll
  for (int hd = 0; hd < 4; ++hd)
    w[hd] = alpha[(size_t)e * 4 + hd] / denom[(size_t)d * 4 + hd];
  const float* hs = h1 + (size_t)s * 256;
  float* od = o1 + (size_t)d * 256;
#pragma unroll
  for (int hd = 0; hd < 4; ++hd) {
    float v = hs[hd * 64 + lane] * w[hd];
    unsafeAtomicAdd(&od[hd * 64 + lane], v);
  }
}

// K5: per-feature sum & sumsq over o1 (coalesced column accumulate)
__global__ __launch_bounds__(256) void k5_bnstats(
    const float* __restrict__ o1, float* __restrict__ bnsum,
    float* __restrict__ bnsq, int N) {
  int f = threadIdx.x;
  float s = 0.f, sq = 0.f;
  for (int n = blockIdx.x; n < N; n += gridDim.x) {
    float v = o1[(size_t)n * 256 + f];
    s += v;
    sq += v * v;
  }
  unsafeAtomicAdd(&bnsum[f], s);
  unsafeAtomicAdd(&bnsq[f], sq);
}

// K6: BN(batch stats) + ELU, in place on o1
__global__ __launch_bounds__(256) void k6_bn_elu(
    float* __restrict__ o1, const float* __restrict__ bnsum,
    const float* __restrict__ bnsq, const float* __restrict__ gamma,
    const float* __restrict__ beta, int N) {
  size_t total = (size_t)N * 256;
  float invN = 1.0f / (float)N;
  for (size_t idx = (size_t)blockIdx.x * 256 + threadIdx.x; idx < total;
       idx += (size_t)gridDim.x * 256) {
    int f = (int)(idx & 255);
    float mu = bnsum[f] * invN;
    float var = bnsq[f] * invN - mu * mu;
    float v = (o1[idx] - mu) * rsqrtf(var + BN_EPS) * gamma[f] + beta[f];
    o1[idx] = v > 0.f ? v : expm1f(v);
  }
}

// K7: h2 = hbn @ W2  [N,64]; a_src2/a_dst2 [N,2]
__global__ __launch_bounds__(256) void k7_linear2(
    const float* __restrict__ hbn, const float* __restrict__ W2,
    const float* __restrict__ att_src2, const float* __restrict__ att_dst2,
    float* __restrict__ h2, float* __restrict__ a_src2, float* __restrict__ a_dst2,
    int N) {
  __shared__ float rows[4][256];
  int wv = threadIdx.x >> 6, lane = threadIdx.x & 63;
  int n = blockIdx.x * 4 + wv;
  bool act = n < N;
  if (act) {
#pragma unroll
    for (int i = 0; i < 4; ++i)
      rows[wv][lane + i * 64] = hbn[(size_t)n * 256 + lane + i * 64];
  }
  __syncthreads();
  if (!act) return;
  float acc = 0.f;
#pragma unroll 8
  for (int k = 0; k < 256; ++k) acc = fmaf(rows[wv][k], W2[k * 64 + lane], acc);
  h2[(size_t)n * 64 + lane] = acc;
  int g = lane >> 5, c = lane & 31;
  float ps = acc * att_src2[g * 32 + c];
  float pd = acc * att_dst2[g * 32 + c];
#pragma unroll
  for (int m = 16; m; m >>= 1) {
    ps += __shfl_xor(ps, m);
    pd += __shfl_xor(pd, m);
  }
  if (c == 0) {
    a_src2[(size_t)n * 2 + g] = ps;
    a_dst2[(size_t)n * 2 + g] = pd;
  }
}

// K8 (layer2): alpha2 + segment max (2 heads)
__global__ void k8_alpha2(const float* __restrict__ a_src, const float* __restrict__ a_dst,
                          const int* __restrict__ src, const int* __restrict__ dst,
                          float* __restrict__ alpha, unsigned* __restrict__ amax,
                          int E, int Et) {
  int e = blockIdx.x * blockDim.x + threadIdx.x;
  if (e >= Et) return;
  int s, d;
  if (e < E) { s = src[e]; d = dst[e]; } else { s = d = e - E; }
#pragma unroll
  for (int hd = 0; hd < 2; ++hd) {
    float a = a_src[(size_t)s * 2 + hd] + a_dst[(size_t)d * 2 + hd];
    a = a >= 0.f ? a : NEG_SLOPE * a;
    alpha[(size_t)e * 2 + hd] = a;
    atomicMax(&amax[(size_t)d * 2 + hd], fmapf(a));
  }
}

// K9 (layer2): exp + denom
__global__ void k9_expsum2(const int* __restrict__ dst,
                           float* __restrict__ alpha, const unsigned* __restrict__ amax,
                           float* __restrict__ denom, int E, int Et) {
  int e = blockIdx.x * blockDim.x + threadIdx.x;
  if (e >= Et) return;
  int d = (e < E) ? dst[e] : (e - E);
#pragma unroll
  for (int hd = 0; hd < 2; ++hd) {
    float m = funmapf(amax[(size_t)d * 2 + hd]);
    float ev = __expf(alpha[(size_t)e * 2 + hd] - m);
    alpha[(size_t)e * 2 + hd] = ev;
    unsafeAtomicAdd(&denom[(size_t)d * 2 + hd], ev);
  }
}

// K10 (layer2): o2[d] += h2[s] * w; one wave per edge, 64 feats (head = lane>>5)
__global__ __launch_bounds__(256) void k10_aggregate2(
    const float* __restrict__ h2, const float* __restrict__ alpha,
    const float* __restrict__ denom,
    const int* __restrict__ src, const int* __restrict__ dst,
    float* __restrict__ o2, int E, int Et) {
  int gid = blockIdx.x * blockDim.x + threadIdx.x;
  int e = gid >> 6;
  if (e >= Et) return;
  int lane = threadIdx.x & 63;
  int s, d;
  if (e < E) { s = src[e]; d = dst[e]; } else { s = d = e - E; }
  int hd = lane >> 5;
  float w = alpha[(size_t)e * 2 + hd] / denom[(size_t)d * 2 + hd];
  float v = h2[(size_t)s * 64 + lane] * w;
  unsafeAtomicAdd(&o2[(size_t)d * 64 + lane], v);
}

// K11: head-mean + b2 -> ELU -> dot Wc -> + bc ; 32 lanes per node
__global__ __launch_bounds__(256) void k11_head(
    const float* __restrict__ o2, const float* __restrict__ b2,
    const float* __restrict__ Wc, const float* __restrict__ bc,
    float* __restrict__ out, int N) {
  int idx = blockIdx.x * blockDim.x + threadIdx.x;
  int n = idx >> 5;
  if (n >= N) return;
  int c = idx & 31;
  float m = 0.5f * (o2[(size_t)n * 64 + c] + o2[(size_t)n * 64 + 32 + c]) + b2[c];
  m = m > 0.f ? m : expm1f(m);
  float t = m * Wc[c];
#pragma unroll
  for (int mk = 16; mk; mk >>= 1) t += __shfl_xor(t, mk);
  if (c == 0) out[n] = t + bc[0];
}

extern "C" void kernel_launch(void* const* d_in, const int* in_sizes, int n_in,
                              void* d_out, int out_size, void* d_ws, size_t ws_size,
                              hipStream_t stream) {
  const float* x = (const float*)d_in[0];
  const int* ei = (const int*)d_in[1];
  const float* W1 = (const float*)d_in[2];
  const float* as1 = (const float*)d_in[3];
  const float* ad1 = (const float*)d_in[4];
  // d_in[5] = b1: cancels exactly under BatchNorm -> unused
  const float* gamma1 = (const float*)d_in[6];
  const float* beta1 = (const float*)d_in[7];
  const float* W2 = (const float*)d_in[8];
  const float* as2 = (const float*)d_in[9];
  const float* ad2 = (const float*)d_in[10];
  const float* b2 = (const float*)d_in[11];
  const float* Wc = (const float*)d_in[12];
  const float* bc = (const float*)d_in[13];

  const int N = in_sizes[0] / 13;
  const int E = in_sizes[1] / 2;
  const int Et = E + N;  // + self loops
  const int* srcp = ei;
  const int* dstp = ei + E;

  float* ws = (float*)d_ws;
  size_t off = 0;
  float* A = ws + off;      off += (size_t)N * 256;  // h1, later layer-2 pool
  float* O1 = ws + off;     off += (size_t)N * 256;
  float* ASRC1 = ws + off;  off += (size_t)N * 4;
  float* ADST1 = ws + off;  off += (size_t)N * 4;
  unsigned* AMAX1 = (unsigned*)(ws + off); off += (size_t)N * 4;
  float* DEN1 = ws + off;   off += (size_t)N * 4;
  float* BNSUM = ws + off;  off += 256;
  float* BNSQ = ws + off;   off += 256;
  float* ALPHA1 = ws + off; off += (size_t)Et * 4;
  // layer-2 buffers alias the (dead after K4) h1 region:
  float* O2 = A;                                 // N*64
  unsigned* AMAX2 = (unsigned*)(A + (size_t)N * 64);  // N*2
  float* DEN2 = A + (size_t)N * 66;              // N*2
  float* H2 = A + (size_t)N * 68;                // N*64
  float* ASRC2 = A + (size_t)N * 132;            // N*2
  float* ADST2 = A + (size_t)N * 134;            // N*2
  float* ALPHA2 = A + (size_t)N * 136;           // Et*2

  // zero: O1 + a_src1/a_dst1/amax1/denom1 + bn stats (contiguous span)
  hipMemsetAsync(O1, 0, ((size_t)N * (256 + 16) + 512) * sizeof(float), stream);

  k1_linear1<<<N, 256, 0, stream>>>(x, W1, as1, ad1, A, ASRC1, ADST1, N);

  int eb = (Et + 255) / 256;
  k2_alpha1<<<eb, 256, 0, stream>>>(ASRC1, ADST1, srcp, dstp, ALPHA1, AMAX1, E, Et);
  k3_expsum1<<<eb, 256, 0, stream>>>(dstp, ALPHA1, AMAX1, DEN1, E, Et);

  int wb1 = (int)(((size_t)Et * 64 + 255) / 256);
  k4_aggregate1<<<wb1, 256, 0, stream>>>(A, ALPHA1, DEN1, srcp, dstp, O1, E, Et);

  k5_bnstats<<<512, 256, 0, stream>>>(O1, BNSUM, BNSQ, N);
  k6_bn_elu<<<4096, 256, 0, stream>>>(O1, BNSUM, BNSQ, gamma1, beta1, N);

  // zero layer-2 accumulators: o2 + amax2 + denom2 (contiguous at A)
  hipMemsetAsync(O2, 0, (size_t)N * 68 * sizeof(float), stream);

  k7_linear2<<<(N + 3) / 4, 256, 0, stream>>>(O1, W2, as2, ad2, H2, ASRC2, ADST2, N);
  k8_alpha2<<<eb, 256, 0, stream>>>(ASRC2, ADST2, srcp, dstp, ALPHA2, AMAX2, E, Et);
  k9_expsum2<<<eb, 256, 0, stream>>>(dstp, ALPHA2, AMAX2, DEN2, E, Et);
  k10_aggregate2<<<wb1, 256, 0, stream>>>(H2, ALPHA2, DEN2, srcp, dstp, O2, E, Et);

  k11_head<<<(int)(((size_t)N * 32 + 255) / 256), 256, 0, stream>>>(
      O2, b2, Wc, bc, (float*)d_out, N);
}

// Round 9
// 686.299 us; speedup vs baseline: 2.3407x; 2.3407x over previous
//
#include <hip/hip_runtime.h>
#include <cstdint>
#include <cstddef>

// ---------------------------------------------------------------------------
// BurnoutGAT round 9 (= round-6 CSR plan, resubmitted through infra failures):
// CSR-by-dst gather aggregation (no f32 scatter atomics).
// Evidence (round 5): k4 WRITE_SIZE=850MB (atomic write-through), FETCH=466MB
// (L2/L3 thrashed by atomic stream). CSR built once per launch, reused twice.
// ---------------------------------------------------------------------------

#define NEG_SLOPE 0.2f
#define BN_EPS 1e-5f

// K1: h1 = x @ W1  [N,256]; a_src1/a_dst1 [N,4] (per-head dot with att vecs)
__global__ __launch_bounds__(256) void k1_linear1(
    const float* __restrict__ x, const float* __restrict__ W1,
    const float* __restrict__ att_src1, const float* __restrict__ att_dst1,
    float* __restrict__ h1, float* __restrict__ a_src1, float* __restrict__ a_dst1,
    int N) {
  __shared__ float xs[13];
  int n = blockIdx.x;
  int f = threadIdx.x;
  if (f < 13) xs[f] = x[(size_t)n * 13 + f];
  __syncthreads();
  float acc = 0.f;
#pragma unroll
  for (int k = 0; k < 13; ++k) acc = fmaf(xs[k], W1[k * 256 + f], acc);
  h1[(size_t)n * 256 + f] = acc;
  int lane = f & 63, wv = f >> 6;  // wave wv == head wv (64 ch per head)
  float ps = acc * att_src1[f];
  float pd = acc * att_dst1[f];
#pragma unroll
  for (int m = 32; m; m >>= 1) {
    ps += __shfl_xor(ps, m);
    pd += __shfl_xor(pd, m);
  }
  if (lane == 0) {
    a_src1[(size_t)n * 4 + wv] = ps;
    a_dst1[(size_t)n * 4 + wv] = pd;
  }
}

// CSR build 1/3: in-degree histogram (incl. self loops). curs must be 0.
__global__ void kc_hist(const int* __restrict__ dst, int* __restrict__ curs,
                        int E, int Et) {
  int e = blockIdx.x * blockDim.x + threadIdx.x;
  if (e >= Et) return;
  int d = (e < E) ? dst[e] : (e - E);
  atomicAdd(&curs[d], 1);
}

// CSR build 2/3: exclusive scan of curs[0..N) -> rowptr[0..N]; curs := rowptr copy.
__global__ __launch_bounds__(1024) void kc_scan(int* __restrict__ curs,
                                                int* __restrict__ rowptr, int N) {
  __shared__ int sdata[1024];
  int t = threadIdx.x;
  int C = (N + 1023) / 1024;
  int base = t * C;
  int part = 0;
  for (int i = 0; i < C; ++i) {
    int idx = base + i;
    if (idx < N) part += curs[idx];
  }
  sdata[t] = part;
  __syncthreads();
  // Hillis-Steele inclusive scan
  for (int o = 1; o < 1024; o <<= 1) {
    int v = (t >= o) ? sdata[t - o] : 0;
    __syncthreads();
    sdata[t] += v;
    __syncthreads();
  }
  int excl = sdata[t] - part;
  if (t == 1023) rowptr[N] = sdata[1023];
  int run = excl;
  for (int i = 0; i < C; ++i) {
    int idx = base + i;
    if (idx < N) {
      int v = curs[idx];
      rowptr[idx] = run;
      curs[idx] = run;  // scatter cursor starts at row base
      run += v;
    }
  }
}

// CSR build 3/3: scatter src ids into dst-sorted order.
__global__ void kc_scatter(const int* __restrict__ src, const int* __restrict__ dst,
                           int* __restrict__ curs, int* __restrict__ csrs,
                           int E, int Et) {
  int e = blockIdx.x * blockDim.x + threadIdx.x;
  if (e >= Et) return;
  int s, d;
  if (e < E) { s = src[e]; d = dst[e]; } else { s = d = e - E; }
  int pos = atomicAdd(&curs[d], 1);
  csrs[pos] = s;
}

// Fused layer-1 softmax+aggregate: one wave per dst node.
// out[d] = (sum_e exp(l_e) * h1[s_e]) / (sum_e exp(l_e))  -- max-free softmax.
__global__ __launch_bounds__(256) void k_agg1(
    const float* __restrict__ h1, const float* __restrict__ as1,
    const float* __restrict__ ad1, const int* __restrict__ rowptr,
    const int* __restrict__ csrs, float* __restrict__ o1, int N) {
  int wv = threadIdx.x >> 6, lane = threadIdx.x & 63;
  int d = blockIdx.x * 4 + wv;
  if (d >= N) return;
  int r0 = rowptr[d], r1 = rowptr[d + 1];
  float4 ad = *(const float4*)(ad1 + (size_t)d * 4);
  float f0 = 0.f, f1 = 0.f, f2 = 0.f, f3 = 0.f;       // features hd*64+lane
  float s0 = 0.f, s1 = 0.f, s2 = 0.f, s3 = 0.f;       // per-head exp sums
  for (int base = r0; base < r1; base += 64) {
    int cd = min(64, r1 - base);
    int s = 0;
    float e0 = 0.f, e1 = 0.f, e2 = 0.f, e3 = 0.f;
    if (lane < cd) {
      s = csrs[base + lane];
      float4 as = *(const float4*)(as1 + (size_t)s * 4);
      float l0 = as.x + ad.x; l0 = l0 >= 0.f ? l0 : NEG_SLOPE * l0;
      float l1 = as.y + ad.y; l1 = l1 >= 0.f ? l1 : NEG_SLOPE * l1;
      float l2 = as.z + ad.z; l2 = l2 >= 0.f ? l2 : NEG_SLOPE * l2;
      float l3 = as.w + ad.w; l3 = l3 >= 0.f ? l3 : NEG_SLOPE * l3;
      e0 = __expf(l0); e1 = __expf(l1); e2 = __expf(l2); e3 = __expf(l3);
      s0 += e0; s1 += e1; s2 += e2; s3 += e3;
    }
    for (int k = 0; k < cd; ++k) {
      int sk = __shfl(s, k);
      float w0 = __shfl(e0, k), w1 = __shfl(e1, k);
      float w2 = __shfl(e2, k), w3 = __shfl(e3, k);
      const float* hp = h1 + (size_t)sk * 256;
      f0 = fmaf(w0, hp[lane], f0);
      f1 = fmaf(w1, hp[64 + lane], f1);
      f2 = fmaf(w2, hp[128 + lane], f2);
      f3 = fmaf(w3, hp[192 + lane], f3);
    }
  }
#pragma unroll
  for (int m = 32; m; m >>= 1) {
    s0 += __shfl_xor(s0, m); s1 += __shfl_xor(s1, m);
    s2 += __shfl_xor(s2, m); s3 += __shfl_xor(s3, m);
  }
  float* op = o1 + (size_t)d * 256;
  op[lane] = f0 / s0;
  op[64 + lane] = f1 / s1;
  op[128 + lane] = f2 / s2;
  op[192 + lane] = f3 / s3;
}

// K5: per-feature sum & sumsq over o1 (coalesced column accumulate)
__global__ __launch_bounds__(256) void k5_bnstats(
    const float* __restrict__ o1, float* __restrict__ bnsum,
    float* __restrict__ bnsq, int N) {
  int f = threadIdx.x;
  float s = 0.f, sq = 0.f;
  for (int n = blockIdx.x; n < N; n += gridDim.x) {
    float v = o1[(size_t)n * 256 + f];
    s += v;
    sq += v * v;
  }
  unsafeAtomicAdd(&bnsum[f], s);
  unsafeAtomicAdd(&bnsq[f], sq);
}

// K6: BN(batch stats) + ELU, in place on o1
__global__ __launch_bounds__(256) void k6_bn_elu(
    float* __restrict__ o1, const float* __restrict__ bnsum,
    const float* __restrict__ bnsq, const float* __restrict__ gamma,
    const float* __restrict__ beta, int N) {
  size_t total = (size_t)N * 256;
  float invN = 1.0f / (float)N;
  for (size_t idx = (size_t)blockIdx.x * 256 + threadIdx.x; idx < total;
       idx += (size_t)gridDim.x * 256) {
    int f = (int)(idx & 255);
    float mu = bnsum[f] * invN;
    float var = bnsq[f] * invN - mu * mu;
    float v = (o1[idx] - mu) * rsqrtf(var + BN_EPS) * gamma[f] + beta[f];
    o1[idx] = v > 0.f ? v : expm1f(v);
  }
}

// K7: h2 = hbn @ W2  [N,64]; a_src2/a_dst2 [N,2]
__global__ __launch_bounds__(256) void k7_linear2(
    const float* __restrict__ hbn, const float* __restrict__ W2,
    const float* __restrict__ att_src2, const float* __restrict__ att_dst2,
    float* __restrict__ h2, float* __restrict__ a_src2, float* __restrict__ a_dst2,
    int N) {
  __shared__ float rows[4][256];
  int wv = threadIdx.x >> 6, lane = threadIdx.x & 63;
  int n = blockIdx.x * 4 + wv;
  bool act = n < N;
  if (act) {
#pragma unroll
    for (int i = 0; i < 4; ++i)
      rows[wv][lane + i * 64] = hbn[(size_t)n * 256 + lane + i * 64];
  }
  __syncthreads();
  if (!act) return;
  float acc = 0.f;
#pragma unroll 8
  for (int k = 0; k < 256; ++k) acc = fmaf(rows[wv][k], W2[k * 64 + lane], acc);
  h2[(size_t)n * 64 + lane] = acc;
  int g = lane >> 5, c = lane & 31;
  float ps = acc * att_src2[g * 32 + c];
  float pd = acc * att_dst2[g * 32 + c];
#pragma unroll
  for (int m = 16; m; m >>= 1) {
    ps += __shfl_xor(ps, m);
    pd += __shfl_xor(pd, m);
  }
  if (c == 0) {
    a_src2[(size_t)n * 2 + g] = ps;
    a_dst2[(size_t)n * 2 + g] = pd;
  }
}

// Fused layer-2 softmax+aggregate: wave per dst, 64 feats (head = lane>>5).
__global__ __launch_bounds__(256) void k_agg2(
    const float* __restrict__ h2, const float* __restrict__ as2,
    const float* __restrict__ ad2, const int* __restrict__ rowptr,
    const int* __restrict__ csrs, float* __restrict__ o2, int N) {
  int wv = threadIdx.x >> 6, lane = threadIdx.x & 63;
  int d = blockIdx.x * 4 + wv;
  if (d >= N) return;
  int r0 = rowptr[d], r1 = rowptr[d + 1];
  float2 ad = *(const float2*)(ad2 + (size_t)d * 2);
  int head = lane >> 5;
  float fa = 0.f, s0 = 0.f, s1 = 0.f;
  for (int base = r0; base < r1; base += 64) {
    int cd = min(64, r1 - base);
    int s = 0;
    float e0 = 0.f, e1 = 0.f;
    if (lane < cd) {
      s = csrs[base + lane];
      float2 as = *(const float2*)(as2 + (size_t)s * 2);
      float l0 = as.x + ad.x; l0 = l0 >= 0.f ? l0 : NEG_SLOPE * l0;
      float l1 = as.y + ad.y; l1 = l1 >= 0.f ? l1 : NEG_SLOPE * l1;
      e0 = __expf(l0); e1 = __expf(l1);
      s0 += e0; s1 += e1;
    }
    for (int k = 0; k < cd; ++k) {
      int sk = __shfl(s, k);
      float w0 = __shfl(e0, k), w1 = __shfl(e1, k);
      float v = h2[(size_t)sk * 64 + lane];
      fa = fmaf(head ? w1 : w0, v, fa);
    }
  }
#pragma unroll
  for (int m = 32; m; m >>= 1) {
    s0 += __shfl_xor(s0, m);
    s1 += __shfl_xor(s1, m);
  }
  o2[(size_t)d * 64 + lane] = fa / (head ? s1 : s0);
}

// K11: head-mean + b2 -> ELU -> dot Wc -> + bc ; 32 lanes per node
__global__ __launch_bounds__(256) void k11_head(
    const float* __restrict__ o2, const float* __restrict__ b2,
    const float* __restrict__ Wc, const float* __restrict__ bc,
    float* __restrict__ out, int N) {
  int idx = blockIdx.x * blockDim.x + threadIdx.x;
  int n = idx >> 5;
  if (n >= N) return;
  int c = idx & 31;
  float m = 0.5f * (o2[(size_t)n * 64 + c] + o2[(size_t)n * 64 + 32 + c]) + b2[c];
  m = m > 0.f ? m : expm1f(m);
  float t = m * Wc[c];
#pragma unroll
  for (int mk = 16; mk; mk >>= 1) t += __shfl_xor(t, mk);
  if (c == 0) out[n] = t + bc[0];
}

extern "C" void kernel_launch(void* const* d_in, const int* in_sizes, int n_in,
                              void* d_out, int out_size, void* d_ws, size_t ws_size,
                              hipStream_t stream) {
  const float* x = (const float*)d_in[0];
  const int* ei = (const int*)d_in[1];
  const float* W1 = (const float*)d_in[2];
  const float* as1 = (const float*)d_in[3];
  const float* ad1 = (const float*)d_in[4];
  // d_in[5] = b1: cancels exactly under BatchNorm -> unused
  const float* gamma1 = (const float*)d_in[6];
  const float* beta1 = (const float*)d_in[7];
  const float* W2 = (const float*)d_in[8];
  const float* as2w = (const float*)d_in[9];
  const float* ad2w = (const float*)d_in[10];
  const float* b2 = (const float*)d_in[11];
  const float* Wc = (const float*)d_in[12];
  const float* bc = (const float*)d_in[13];

  const int N = in_sizes[0] / 13;
  const int E = in_sizes[1] / 2;
  const int Et = E + N;  // + self loops
  const int* srcp = ei;
  const int* dstp = ei + E;

  float* ws = (float*)d_ws;
  float* H1 = ws;                                // N*256 (layer-2 pool later)
  float* O1 = H1 + (size_t)N * 256;              // N*256
  float* AS1 = O1 + (size_t)N * 256;             // N*4
  float* AD1 = AS1 + (size_t)N * 4;              // N*4
  float* BNS = AD1 + (size_t)N * 4;              // 256
  float* BNQ = BNS + 256;                        // 256
  int* ROWPTR = (int*)(BNQ + 256);               // N+1
  int* CURS = ROWPTR + (N + 1);                  // N
  int* CSRS = CURS + N;                          // Et
  // layer-2 aliases into dead H1 region:
  float* O2 = H1;                                // N*64
  float* H2 = H1 + (size_t)N * 64;               // N*64
  float* AS2 = H1 + (size_t)N * 128;             // N*2
  float* AD2 = H1 + (size_t)N * 130;             // N*2

  // zero the atomic targets (ws is poisoned 0xAA before every launch)
  hipMemsetAsync(CURS, 0, (size_t)N * sizeof(int), stream);
  hipMemsetAsync(BNS, 0, 512 * sizeof(float), stream);

  int eb = (Et + 255) / 256;
  // CSR build (shared by both layers)
  kc_hist<<<eb, 256, 0, stream>>>(dstp, CURS, E, Et);
  kc_scan<<<1, 1024, 0, stream>>>(CURS, ROWPTR, N);
  kc_scatter<<<eb, 256, 0, stream>>>(srcp, dstp, CURS, CSRS, E, Et);

  // layer 1
  k1_linear1<<<N, 256, 0, stream>>>(x, W1, as1, ad1, H1, AS1, AD1, N);
  k_agg1<<<(N + 3) / 4, 256, 0, stream>>>(H1, AS1, AD1, ROWPTR, CSRS, O1, N);
  k5_bnstats<<<512, 256, 0, stream>>>(O1, BNS, BNQ, N);
  k6_bn_elu<<<4096, 256, 0, stream>>>(O1, BNS, BNQ, gamma1, beta1, N);

  // layer 2
  k7_linear2<<<(N + 3) / 4, 256, 0, stream>>>(O1, W2, as2w, ad2w, H2, AS2, AD2, N);
  k_agg2<<<(N + 3) / 4, 256, 0, stream>>>(H2, AS2, AD2, ROWPTR, CSRS, O2, N);

  k11_head<<<(int)(((size_t)N * 32 + 255) / 256), 256, 0, stream>>>(
      O2, b2, Wc, bc, (float*)d_out, N);
}

// Round 11
// 630.873 us; speedup vs baseline: 2.5464x; 1.0879x over previous
//
#include <hip/hip_runtime.h>
#include <cstdint>
#include <cstddef>

// ---------------------------------------------------------------------------
// BurnoutGAT round 11 (= round-10 reassociation plan, resubmitted after infra
// failure). Layer-1 reassociation: o1 = (A_hat@x)@W1 and a_src = x.(W1@att)
// -- h1 [N,256] never materialized; gather moves from 1KB h1 rows (425MB
// L2-miss FETCH measured in round 9) to 52B x rows (L2-resident).
// CSR-by-dst gather (round 9, validated). BN-stats fused into dense expand;
// head-mean/ELU/Wc fused into layer-2 aggregate.
// ---------------------------------------------------------------------------

#define NEG_SLOPE 0.2f
#define BN_EPS 1e-5f

// KP: project attention vectors through W1: CS/CD[13][4]
// CS[k][h] = sum_c W1[k, h*64+c] * att_src1[h, c]
__global__ __launch_bounds__(64) void kp_proj(
    const float* __restrict__ W1, const float* __restrict__ att_src1,
    const float* __restrict__ att_dst1, float* __restrict__ CS,
    float* __restrict__ CD) {
  int t = threadIdx.x;
  if (t >= 52) return;
  int k = t >> 2, h = t & 3;
  float cs = 0.f, cd = 0.f;
#pragma unroll 8
  for (int c = 0; c < 64; ++c) {
    float w = W1[k * 256 + h * 64 + c];
    cs = fmaf(w, att_src1[h * 64 + c], cs);
    cd = fmaf(w, att_dst1[h * 64 + c], cd);
  }
  CS[k * 4 + h] = cs;
  CD[k * 4 + h] = cd;
}

// KA: per-node logits from x directly: a_src[n][h] = sum_k x[n][k]*CS[k][h]
__global__ __launch_bounds__(256) void ka_logits(
    const float* __restrict__ x, const float* __restrict__ CS,
    const float* __restrict__ CD, float* __restrict__ as1,
    float* __restrict__ ad1, int N) {
  int n = blockIdx.x * blockDim.x + threadIdx.x;
  if (n >= N) return;
  float xr[13];
#pragma unroll
  for (int k = 0; k < 13; ++k) xr[k] = x[(size_t)n * 13 + k];
#pragma unroll
  for (int h = 0; h < 4; ++h) {
    float as = 0.f, ad = 0.f;
#pragma unroll
    for (int k = 0; k < 13; ++k) {
      as = fmaf(xr[k], CS[k * 4 + h], as);
      ad = fmaf(xr[k], CD[k * 4 + h], ad);
    }
    as1[(size_t)n * 4 + h] = as;
    ad1[(size_t)n * 4 + h] = ad;
  }
}

// CSR build 1/3: in-degree histogram (incl. self loops). curs must be 0.
__global__ void kc_hist(const int* __restrict__ dst, int* __restrict__ curs,
                        int E, int Et) {
  int e = blockIdx.x * blockDim.x + threadIdx.x;
  if (e >= Et) return;
  int d = (e < E) ? dst[e] : (e - E);
  atomicAdd(&curs[d], 1);
}

// CSR build 2/3: exclusive scan of curs[0..N) -> rowptr[0..N]; curs := rowptr copy.
__global__ __launch_bounds__(1024) void kc_scan(int* __restrict__ curs,
                                                int* __restrict__ rowptr, int N) {
  __shared__ int sdata[1024];
  int t = threadIdx.x;
  int C = (N + 1023) / 1024;
  int base = t * C;
  int part = 0;
  for (int i = 0; i < C; ++i) {
    int idx = base + i;
    if (idx < N) part += curs[idx];
  }
  sdata[t] = part;
  __syncthreads();
  for (int o = 1; o < 1024; o <<= 1) {
    int v = (t >= o) ? sdata[t - o] : 0;
    __syncthreads();
    sdata[t] += v;
    __syncthreads();
  }
  int excl = sdata[t] - part;
  if (t == 1023) rowptr[N] = sdata[1023];
  int run = excl;
  for (int i = 0; i < C; ++i) {
    int idx = base + i;
    if (idx < N) {
      int v = curs[idx];
      rowptr[idx] = run;
      curs[idx] = run;
      run += v;
    }
  }
}

// CSR build 3/3: scatter src ids into dst-sorted order.
__global__ void kc_scatter(const int* __restrict__ src, const int* __restrict__ dst,
                           int* __restrict__ curs, int* __restrict__ csrs,
                           int E, int Et) {
  int e = blockIdx.x * blockDim.x + threadIdx.x;
  if (e >= Et) return;
  int s, d;
  if (e < E) { s = src[e]; d = dst[e]; } else { s = d = e - E; }
  int pos = atomicAdd(&curs[d], 1);
  csrs[pos] = s;
}

// agg_x: y[d][h][k] = softmax-weighted sum of x[s][k] over in-edges of d.
// Wave per dst. Lanes 0..51: h=lane/13, k=lane%13. Max-free softmax.
__global__ __launch_bounds__(256) void agg_x(
    const float* __restrict__ x, const float* __restrict__ as1,
    const float* __restrict__ ad1, const int* __restrict__ rowptr,
    const int* __restrict__ csrs, float* __restrict__ y, int N) {
  int wv = threadIdx.x >> 6, lane = threadIdx.x & 63;
  int d = blockIdx.x * 4 + wv;
  if (d >= N) return;
  int r0 = rowptr[d], r1 = rowptr[d + 1];
  float4 adv = *(const float4*)(ad1 + (size_t)d * 4);
  int hh = lane / 13;           // 0..3 for lane<52 (>=4 for tail lanes)
  int kk = lane - hh * 13;      // 0..12
  float acc = 0.f;
  float s0 = 0.f, s1 = 0.f, s2 = 0.f, s3 = 0.f;
  for (int base = r0; base < r1; base += 64) {
    int cd = min(64, r1 - base);
    int s = 0;
    float e0 = 0.f, e1 = 0.f, e2 = 0.f, e3 = 0.f;
    if (lane < cd) {
      s = csrs[base + lane];
      float4 av = *(const float4*)(as1 + (size_t)s * 4);
      float l0 = av.x + adv.x; l0 = l0 >= 0.f ? l0 : NEG_SLOPE * l0;
      float l1 = av.y + adv.y; l1 = l1 >= 0.f ? l1 : NEG_SLOPE * l1;
      float l2 = av.z + adv.z; l2 = l2 >= 0.f ? l2 : NEG_SLOPE * l2;
      float l3 = av.w + adv.w; l3 = l3 >= 0.f ? l3 : NEG_SLOPE * l3;
      e0 = __expf(l0); e1 = __expf(l1); e2 = __expf(l2); e3 = __expf(l3);
      s0 += e0; s1 += e1; s2 += e2; s3 += e3;
    }
    for (int k = 0; k < cd; ++k) {
      int sk = __shfl(s, k);
      float w0 = __shfl(e0, k), w1 = __shfl(e1, k);
      float w2 = __shfl(e2, k), w3 = __shfl(e3, k);
      float w = hh == 0 ? w0 : hh == 1 ? w1 : hh == 2 ? w2 : w3;
      float xv = (lane < 52) ? x[(size_t)sk * 13 + kk] : 0.f;
      acc = fmaf(w, xv, acc);
    }
  }
#pragma unroll
  for (int m = 32; m; m >>= 1) {
    s0 += __shfl_xor(s0, m); s1 += __shfl_xor(s1, m);
    s2 += __shfl_xor(s2, m); s3 += __shfl_xor(s3, m);
  }
  if (lane < 52) {
    float den = hh == 0 ? s0 : hh == 1 ? s1 : hh == 2 ? s2 : s3;
    y[(size_t)d * 52 + lane] = acc / den;
  }
}

// k1b: o1[n, h*64+c] = sum_k y[n][h][k] * W1[k, h*64+c]; W1 staged in LDS.
// Fused BN-stats epilogue (per-thread column partials -> 2 atomics).
__global__ __launch_bounds__(256) void k1b_dense(
    const float* __restrict__ y, const float* __restrict__ W1,
    float* __restrict__ o1, float* __restrict__ bnsum,
    float* __restrict__ bnsq, int N) {
  __shared__ float W1s[13 * 256];
  int f = threadIdx.x;
  for (int idx = f; idx < 13 * 256; idx += 256) W1s[idx] = W1[idx];
  __syncthreads();
  int w = f >> 6, lane = f & 63;
  float s = 0.f, sq = 0.f;
  for (int n = blockIdx.x; n < N; n += gridDim.x) {
    float yv = (lane < 13) ? y[(size_t)n * 52 + w * 13 + lane] : 0.f;
    float acc = 0.f;
#pragma unroll
    for (int k = 0; k < 13; ++k)
      acc = fmaf(__shfl(yv, k), W1s[k * 256 + f], acc);
    o1[(size_t)n * 256 + f] = acc;
    s += acc;
    sq += acc * acc;
  }
  unsafeAtomicAdd(&bnsum[f], s);
  unsafeAtomicAdd(&bnsq[f], sq);
}

// K6: BN(batch stats) + ELU, in place on o1
__global__ __launch_bounds__(256) void k6_bn_elu(
    float* __restrict__ o1, const float* __restrict__ bnsum,
    const float* __restrict__ bnsq, const float* __restrict__ gamma,
    const float* __restrict__ beta, int N) {
  size_t total = (size_t)N * 256;
  float invN = 1.0f / (float)N;
  for (size_t idx = (size_t)blockIdx.x * 256 + threadIdx.x; idx < total;
       idx += (size_t)gridDim.x * 256) {
    int f = (int)(idx & 255);
    float mu = bnsum[f] * invN;
    float var = bnsq[f] * invN - mu * mu;
    float v = (o1[idx] - mu) * rsqrtf(var + BN_EPS) * gamma[f] + beta[f];
    o1[idx] = v > 0.f ? v : expm1f(v);
  }
}

// K7: h2 = hbn @ W2  [N,64]; a_src2/a_dst2 [N,2]
__global__ __launch_bounds__(256) void k7_linear2(
    const float* __restrict__ hbn, const float* __restrict__ W2,
    const float* __restrict__ att_src2, const float* __restrict__ att_dst2,
    float* __restrict__ h2, float* __restrict__ a_src2, float* __restrict__ a_dst2,
    int N) {
  __shared__ float rows[4][256];
  int wv = threadIdx.x >> 6, lane = threadIdx.x & 63;
  int n = blockIdx.x * 4 + wv;
  bool act = n < N;
  if (act) {
#pragma unroll
    for (int i = 0; i < 4; ++i)
      rows[wv][lane + i * 64] = hbn[(size_t)n * 256 + lane + i * 64];
  }
  __syncthreads();
  if (!act) return;
  float acc = 0.f;
#pragma unroll 8
  for (int k = 0; k < 256; ++k) acc = fmaf(rows[wv][k], W2[k * 64 + lane], acc);
  h2[(size_t)n * 64 + lane] = acc;
  int g = lane >> 5, c = lane & 31;
  float ps = acc * att_src2[g * 32 + c];
  float pd = acc * att_dst2[g * 32 + c];
#pragma unroll
  for (int m = 16; m; m >>= 1) {
    ps += __shfl_xor(ps, m);
    pd += __shfl_xor(pd, m);
  }
  if (c == 0) {
    a_src2[(size_t)n * 2 + g] = ps;
    a_dst2[(size_t)n * 2 + g] = pd;
  }
}

// Fused layer-2 aggregate + head-mean + b2 + ELU + Wc dot + bc.
// Wave per dst, 64 feats (head = lane>>5); o2 never materialized.
__global__ __launch_bounds__(256) void kagg2_head(
    const float* __restrict__ h2, const float* __restrict__ as2,
    const float* __restrict__ ad2, const int* __restrict__ rowptr,
    const int* __restrict__ csrs, const float* __restrict__ b2,
    const float* __restrict__ Wc, const float* __restrict__ bc,
    float* __restrict__ out, int N) {
  int wv = threadIdx.x >> 6, lane = threadIdx.x & 63;
  int d = blockIdx.x * 4 + wv;
  if (d >= N) return;
  int r0 = rowptr[d], r1 = rowptr[d + 1];
  float2 adv = *(const float2*)(ad2 + (size_t)d * 2);
  int head = lane >> 5;
  float fa = 0.f, s0 = 0.f, s1 = 0.f;
  for (int base = r0; base < r1; base += 64) {
    int cd = min(64, r1 - base);
    int s = 0;
    float e0 = 0.f, e1 = 0.f;
    if (lane < cd) {
      s = csrs[base + lane];
      float2 av = *(const float2*)(as2 + (size_t)s * 2);
      float l0 = av.x + adv.x; l0 = l0 >= 0.f ? l0 : NEG_SLOPE * l0;
      float l1 = av.y + adv.y; l1 = l1 >= 0.f ? l1 : NEG_SLOPE * l1;
      e0 = __expf(l0); e1 = __expf(l1);
      s0 += e0; s1 += e1;
    }
    for (int k = 0; k < cd; ++k) {
      int sk = __shfl(s, k);
      float w0 = __shfl(e0, k), w1 = __shfl(e1, k);
      float v = h2[(size_t)sk * 64 + lane];
      fa = fmaf(head ? w1 : w0, v, fa);
    }
  }
#pragma unroll
  for (int m = 32; m; m >>= 1) {
    s0 += __shfl_xor(s0, m);
    s1 += __shfl_xor(s1, m);
  }
  float o2v = fa / (head ? s1 : s0);
  float partner = __shfl_xor(o2v, 32);
  if (lane < 32) {
    float m = 0.5f * (o2v + partner) + b2[lane];
    m = m > 0.f ? m : expm1f(m);
    float t = m * Wc[lane];
#pragma unroll
    for (int mk = 16; mk; mk >>= 1) t += __shfl_xor(t, mk);
    if (lane == 0) out[d] = t + bc[0];
  }
}

extern "C" void kernel_launch(void* const* d_in, const int* in_sizes, int n_in,
                              void* d_out, int out_size, void* d_ws, size_t ws_size,
                              hipStream_t stream) {
  const float* x = (const float*)d_in[0];
  const int* ei = (const int*)d_in[1];
  const float* W1 = (const float*)d_in[2];
  const float* as1w = (const float*)d_in[3];
  const float* ad1w = (const float*)d_in[4];
  // d_in[5] = b1: cancels exactly under BatchNorm -> unused
  const float* gamma1 = (const float*)d_in[6];
  const float* beta1 = (const float*)d_in[7];
  const float* W2 = (const float*)d_in[8];
  const float* as2w = (const float*)d_in[9];
  const float* ad2w = (const float*)d_in[10];
  const float* b2 = (const float*)d_in[11];
  const float* Wc = (const float*)d_in[12];
  const float* bc = (const float*)d_in[13];

  const int N = in_sizes[0] / 13;
  const int E = in_sizes[1] / 2;
  const int Et = E + N;  // + self loops
  const int* srcp = ei;
  const int* dstp = ei + E;

  float* ws = (float*)d_ws;
  float* O1 = ws;                                // N*256
  float* Y = O1 + (size_t)N * 256;               // N*52
  float* AS1 = Y + (size_t)N * 52;               // N*4 (16B aligned)
  float* AD1 = AS1 + (size_t)N * 4;              // N*4
  float* H2 = AD1 + (size_t)N * 4;               // N*64
  float* AS2 = H2 + (size_t)N * 64;              // N*2
  float* AD2 = AS2 + (size_t)N * 2;              // N*2
  float* CS = AD2 + (size_t)N * 2;               // 64 (52 used)
  float* CD = CS + 64;                           // 64
  float* BNS = CD + 64;                          // 256
  float* BNQ = BNS + 256;                        // 256
  int* ROWPTR = (int*)(BNQ + 256);               // N+1
  int* CURS = ROWPTR + (N + 1);                  // N
  int* CSRS = CURS + N;                          // Et

  // zero the atomic accumulators (ws is re-poisoned before every launch)
  hipMemsetAsync(CURS, 0, (size_t)N * sizeof(int), stream);
  hipMemsetAsync(BNS, 0, 512 * sizeof(float), stream);

  int eb = (Et + 255) / 256;
  // CSR build (shared by both layers)
  kc_hist<<<eb, 256, 0, stream>>>(dstp, CURS, E, Et);
  kc_scan<<<1, 1024, 0, stream>>>(CURS, ROWPTR, N);
  kc_scatter<<<eb, 256, 0, stream>>>(srcp, dstp, CURS, CSRS, E, Et);

  // layer 1 (h1 never materialized)
  kp_proj<<<1, 64, 0, stream>>>(W1, as1w, ad1w, CS, CD);
  ka_logits<<<(N + 255) / 256, 256, 0, stream>>>(x, CS, CD, AS1, AD1, N);
  agg_x<<<(N + 3) / 4, 256, 0, stream>>>(x, AS1, AD1, ROWPTR, CSRS, Y, N);
  k1b_dense<<<256, 256, 0, stream>>>(Y, W1, O1, BNS, BNQ, N);
  k6_bn_elu<<<4096, 256, 0, stream>>>(O1, BNS, BNQ, gamma1, beta1, N);

  // layer 2
  k7_linear2<<<(N + 3) / 4, 256, 0, stream>>>(O1, W2, as2w, ad2w, H2, AS2, AD2, N);
  kagg2_head<<<(N + 3) / 4, 256, 0, stream>>>(H2, AS2, AD2, ROWPTR, CSRS,
                                              b2, Wc, bc, (float*)d_out, N);
}

// Round 13
// 520.869 us; speedup vs baseline: 3.0842x; 1.2112x over previous
//
#include <hip/hip_runtime.h>
#include <cstdint>
#include <cstddef>

// ---------------------------------------------------------------------------
// BurnoutGAT round 13 (= round-12 scan fix, resubmitted after infra failure):
// round-11 (reassociation, validated 631us) + replace the single-block
// kc_scan (measured 127us, VALUBusy 0.01%, 1-CU latency disaster) with a
// 3-pass hierarchical scan (~12us). No other changes.
// ---------------------------------------------------------------------------

#define NEG_SLOPE 0.2f
#define BN_EPS 1e-5f

// KP: project attention vectors through W1: CS/CD[13][4]
__global__ __launch_bounds__(64) void kp_proj(
    const float* __restrict__ W1, const float* __restrict__ att_src1,
    const float* __restrict__ att_dst1, float* __restrict__ CS,
    float* __restrict__ CD) {
  int t = threadIdx.x;
  if (t >= 52) return;
  int k = t >> 2, h = t & 3;
  float cs = 0.f, cd = 0.f;
#pragma unroll 8
  for (int c = 0; c < 64; ++c) {
    float w = W1[k * 256 + h * 64 + c];
    cs = fmaf(w, att_src1[h * 64 + c], cs);
    cd = fmaf(w, att_dst1[h * 64 + c], cd);
  }
  CS[k * 4 + h] = cs;
  CD[k * 4 + h] = cd;
}

// KA: per-node logits from x directly
__global__ __launch_bounds__(256) void ka_logits(
    const float* __restrict__ x, const float* __restrict__ CS,
    const float* __restrict__ CD, float* __restrict__ as1,
    float* __restrict__ ad1, int N) {
  int n = blockIdx.x * blockDim.x + threadIdx.x;
  if (n >= N) return;
  float xr[13];
#pragma unroll
  for (int k = 0; k < 13; ++k) xr[k] = x[(size_t)n * 13 + k];
#pragma unroll
  for (int h = 0; h < 4; ++h) {
    float as = 0.f, ad = 0.f;
#pragma unroll
    for (int k = 0; k < 13; ++k) {
      as = fmaf(xr[k], CS[k * 4 + h], as);
      ad = fmaf(xr[k], CD[k * 4 + h], ad);
    }
    as1[(size_t)n * 4 + h] = as;
    ad1[(size_t)n * 4 + h] = ad;
  }
}

// CSR build 1: in-degree histogram (incl. self loops). curs must be 0.
__global__ void kc_hist(const int* __restrict__ dst, int* __restrict__ curs,
                        int E, int Et) {
  int e = blockIdx.x * blockDim.x + threadIdx.x;
  if (e >= Et) return;
  int d = (e < E) ? dst[e] : (e - E);
  atomicAdd(&curs[d], 1);
}

// CSR scan pass 1: per-block exclusive scan of curs -> rowptr (block-local);
// block totals -> blocksum.
__global__ __launch_bounds__(1024) void kc_scan1(
    const int* __restrict__ curs, int* __restrict__ rowptr,
    int* __restrict__ blocksum, int N) {
  __shared__ int sdata[1024];
  int t = threadIdx.x;
  int gid = blockIdx.x * 1024 + t;
  int v = (gid < N) ? curs[gid] : 0;
  sdata[t] = v;
  __syncthreads();
  for (int o = 1; o < 1024; o <<= 1) {
    int u = (t >= o) ? sdata[t - o] : 0;
    __syncthreads();
    sdata[t] += u;
    __syncthreads();
  }
  if (gid < N) rowptr[gid] = sdata[t] - v;  // exclusive within block
  if (t == 1023) blocksum[blockIdx.x] = sdata[1023];
}

// CSR scan pass 2: exclusive scan of blocksum[NB] in place (NB <= 1024).
__global__ __launch_bounds__(1024) void kc_scan2(int* __restrict__ blocksum,
                                                 int NB) {
  __shared__ int sd[1024];
  int t = threadIdx.x;
  int v = (t < NB) ? blocksum[t] : 0;
  sd[t] = v;
  __syncthreads();
  for (int o = 1; o < 1024; o <<= 1) {
    int u = (t >= o) ? sd[t - o] : 0;
    __syncthreads();
    sd[t] += u;
    __syncthreads();
  }
  if (t < NB) blocksum[t] = sd[t] - v;
}

// CSR scan pass 3: add block offsets; write rowptr + curs (cursor copy);
// rowptr[N] = Et (known statically).
__global__ __launch_bounds__(1024) void kc_scan3(
    int* __restrict__ rowptr, int* __restrict__ curs,
    const int* __restrict__ blocksum, int N, int Et) {
  int gid = blockIdx.x * 1024 + threadIdx.x;
  if (gid < N) {
    int val = rowptr[gid] + blocksum[blockIdx.x];
    rowptr[gid] = val;
    curs[gid] = val;
  }
  if (gid == 0) rowptr[N] = Et;
}

// CSR build 3: scatter src ids into dst-sorted order.
__global__ void kc_scatter(const int* __restrict__ src, const int* __restrict__ dst,
                           int* __restrict__ curs, int* __restrict__ csrs,
                           int E, int Et) {
  int e = blockIdx.x * blockDim.x + threadIdx.x;
  if (e >= Et) return;
  int s, d;
  if (e < E) { s = src[e]; d = dst[e]; } else { s = d = e - E; }
  int pos = atomicAdd(&curs[d], 1);
  csrs[pos] = s;
}

// agg_x: y[d][h][k] = softmax-weighted sum of x[s][k] over in-edges of d.
__global__ __launch_bounds__(256) void agg_x(
    const float* __restrict__ x, const float* __restrict__ as1,
    const float* __restrict__ ad1, const int* __restrict__ rowptr,
    const int* __restrict__ csrs, float* __restrict__ y, int N) {
  int wv = threadIdx.x >> 6, lane = threadIdx.x & 63;
  int d = blockIdx.x * 4 + wv;
  if (d >= N) return;
  int r0 = rowptr[d], r1 = rowptr[d + 1];
  float4 adv = *(const float4*)(ad1 + (size_t)d * 4);
  int hh = lane / 13;
  int kk = lane - hh * 13;
  float acc = 0.f;
  float s0 = 0.f, s1 = 0.f, s2 = 0.f, s3 = 0.f;
  for (int base = r0; base < r1; base += 64) {
    int cd = min(64, r1 - base);
    int s = 0;
    float e0 = 0.f, e1 = 0.f, e2 = 0.f, e3 = 0.f;
    if (lane < cd) {
      s = csrs[base + lane];
      float4 av = *(const float4*)(as1 + (size_t)s * 4);
      float l0 = av.x + adv.x; l0 = l0 >= 0.f ? l0 : NEG_SLOPE * l0;
      float l1 = av.y + adv.y; l1 = l1 >= 0.f ? l1 : NEG_SLOPE * l1;
      float l2 = av.z + adv.z; l2 = l2 >= 0.f ? l2 : NEG_SLOPE * l2;
      float l3 = av.w + adv.w; l3 = l3 >= 0.f ? l3 : NEG_SLOPE * l3;
      e0 = __expf(l0); e1 = __expf(l1); e2 = __expf(l2); e3 = __expf(l3);
      s0 += e0; s1 += e1; s2 += e2; s3 += e3;
    }
    for (int k = 0; k < cd; ++k) {
      int sk = __shfl(s, k);
      float w0 = __shfl(e0, k), w1 = __shfl(e1, k);
      float w2 = __shfl(e2, k), w3 = __shfl(e3, k);
      float w = hh == 0 ? w0 : hh == 1 ? w1 : hh == 2 ? w2 : w3;
      float xv = (lane < 52) ? x[(size_t)sk * 13 + kk] : 0.f;
      acc = fmaf(w, xv, acc);
    }
  }
#pragma unroll
  for (int m = 32; m; m >>= 1) {
    s0 += __shfl_xor(s0, m); s1 += __shfl_xor(s1, m);
    s2 += __shfl_xor(s2, m); s3 += __shfl_xor(s3, m);
  }
  if (lane < 52) {
    float den = hh == 0 ? s0 : hh == 1 ? s1 : hh == 2 ? s2 : s3;
    y[(size_t)d * 52 + lane] = acc / den;
  }
}

// k1b: o1[n, h*64+c] = sum_k y[n][h][k] * W1[k, h*64+c]; W1 in LDS.
// Fused BN-stats epilogue.
__global__ __launch_bounds__(256) void k1b_dense(
    const float* __restrict__ y, const float* __restrict__ W1,
    float* __restrict__ o1, float* __restrict__ bnsum,
    float* __restrict__ bnsq, int N) {
  __shared__ float W1s[13 * 256];
  int f = threadIdx.x;
  for (int idx = f; idx < 13 * 256; idx += 256) W1s[idx] = W1[idx];
  __syncthreads();
  int w = f >> 6, lane = f & 63;
  float s = 0.f, sq = 0.f;
  for (int n = blockIdx.x; n < N; n += gridDim.x) {
    float yv = (lane < 13) ? y[(size_t)n * 52 + w * 13 + lane] : 0.f;
    float acc = 0.f;
#pragma unroll
    for (int k = 0; k < 13; ++k)
      acc = fmaf(__shfl(yv, k), W1s[k * 256 + f], acc);
    o1[(size_t)n * 256 + f] = acc;
    s += acc;
    sq += acc * acc;
  }
  unsafeAtomicAdd(&bnsum[f], s);
  unsafeAtomicAdd(&bnsq[f], sq);
}

// K6: BN(batch stats) + ELU, in place on o1
__global__ __launch_bounds__(256) void k6_bn_elu(
    float* __restrict__ o1, const float* __restrict__ bnsum,
    const float* __restrict__ bnsq, const float* __restrict__ gamma,
    const float* __restrict__ beta, int N) {
  size_t total = (size_t)N * 256;
  float invN = 1.0f / (float)N;
  for (size_t idx = (size_t)blockIdx.x * 256 + threadIdx.x; idx < total;
       idx += (size_t)gridDim.x * 256) {
    int f = (int)(idx & 255);
    float mu = bnsum[f] * invN;
    float var = bnsq[f] * invN - mu * mu;
    float v = (o1[idx] - mu) * rsqrtf(var + BN_EPS) * gamma[f] + beta[f];
    o1[idx] = v > 0.f ? v : expm1f(v);
  }
}

// K7: h2 = hbn @ W2  [N,64]; a_src2/a_dst2 [N,2]
__global__ __launch_bounds__(256) void k7_linear2(
    const float* __restrict__ hbn, const float* __restrict__ W2,
    const float* __restrict__ att_src2, const float* __restrict__ att_dst2,
    float* __restrict__ h2, float* __restrict__ a_src2, float* __restrict__ a_dst2,
    int N) {
  __shared__ float rows[4][256];
  int wv = threadIdx.x >> 6, lane = threadIdx.x & 63;
  int n = blockIdx.x * 4 + wv;
  bool act = n < N;
  if (act) {
#pragma unroll
    for (int i = 0; i < 4; ++i)
      rows[wv][lane + i * 64] = hbn[(size_t)n * 256 + lane + i * 64];
  }
  __syncthreads();
  if (!act) return;
  float acc = 0.f;
#pragma unroll 8
  for (int k = 0; k < 256; ++k) acc = fmaf(rows[wv][k], W2[k * 64 + lane], acc);
  h2[(size_t)n * 64 + lane] = acc;
  int g = lane >> 5, c = lane & 31;
  float ps = acc * att_src2[g * 32 + c];
  float pd = acc * att_dst2[g * 32 + c];
#pragma unroll
  for (int m = 16; m; m >>= 1) {
    ps += __shfl_xor(ps, m);
    pd += __shfl_xor(pd, m);
  }
  if (c == 0) {
    a_src2[(size_t)n * 2 + g] = ps;
    a_dst2[(size_t)n * 2 + g] = pd;
  }
}

// Fused layer-2 aggregate + head-mean + b2 + ELU + Wc dot + bc.
__global__ __launch_bounds__(256) void kagg2_head(
    const float* __restrict__ h2, const float* __restrict__ as2,
    const float* __restrict__ ad2, const int* __restrict__ rowptr,
    const int* __restrict__ csrs, const float* __restrict__ b2,
    const float* __restrict__ Wc, const float* __restrict__ bc,
    float* __restrict__ out, int N) {
  int wv = threadIdx.x >> 6, lane = threadIdx.x & 63;
  int d = blockIdx.x * 4 + wv;
  if (d >= N) return;
  int r0 = rowptr[d], r1 = rowptr[d + 1];
  float2 adv = *(const float2*)(ad2 + (size_t)d * 2);
  int head = lane >> 5;
  float fa = 0.f, s0 = 0.f, s1 = 0.f;
  for (int base = r0; base < r1; base += 64) {
    int cd = min(64, r1 - base);
    int s = 0;
    float e0 = 0.f, e1 = 0.f;
    if (lane < cd) {
      s = csrs[base + lane];
      float2 av = *(const float2*)(as2 + (size_t)s * 2);
      float l0 = av.x + adv.x; l0 = l0 >= 0.f ? l0 : NEG_SLOPE * l0;
      float l1 = av.y + adv.y; l1 = l1 >= 0.f ? l1 : NEG_SLOPE * l1;
      e0 = __expf(l0); e1 = __expf(l1);
      s0 += e0; s1 += e1;
    }
    for (int k = 0; k < cd; ++k) {
      int sk = __shfl(s, k);
      float w0 = __shfl(e0, k), w1 = __shfl(e1, k);
      float v = h2[(size_t)sk * 64 + lane];
      fa = fmaf(head ? w1 : w0, v, fa);
    }
  }
#pragma unroll
  for (int m = 32; m; m >>= 1) {
    s0 += __shfl_xor(s0, m);
    s1 += __shfl_xor(s1, m);
  }
  float o2v = fa / (head ? s1 : s0);
  float partner = __shfl_xor(o2v, 32);
  if (lane < 32) {
    float m = 0.5f * (o2v + partner) + b2[lane];
    m = m > 0.f ? m : expm1f(m);
    float t = m * Wc[lane];
#pragma unroll
    for (int mk = 16; mk; mk >>= 1) t += __shfl_xor(t, mk);
    if (lane == 0) out[d] = t + bc[0];
  }
}

extern "C" void kernel_launch(void* const* d_in, const int* in_sizes, int n_in,
                              void* d_out, int out_size, void* d_ws, size_t ws_size,
                              hipStream_t stream) {
  const float* x = (const float*)d_in[0];
  const int* ei = (const int*)d_in[1];
  const float* W1 = (const float*)d_in[2];
  const float* as1w = (const float*)d_in[3];
  const float* ad1w = (const float*)d_in[4];
  // d_in[5] = b1: cancels exactly under BatchNorm -> unused
  const float* gamma1 = (const float*)d_in[6];
  const float* beta1 = (const float*)d_in[7];
  const float* W2 = (const float*)d_in[8];
  const float* as2w = (const float*)d_in[9];
  const float* ad2w = (const float*)d_in[10];
  const float* b2 = (const float*)d_in[11];
  const float* Wc = (const float*)d_in[12];
  const float* bc = (const float*)d_in[13];

  const int N = in_sizes[0] / 13;
  const int E = in_sizes[1] / 2;
  const int Et = E + N;  // + self loops
  const int* srcp = ei;
  const int* dstp = ei + E;

  float* ws = (float*)d_ws;
  float* O1 = ws;                                // N*256
  float* Y = O1 + (size_t)N * 256;               // N*52
  float* AS1 = Y + (size_t)N * 52;               // N*4 (16B aligned)
  float* AD1 = AS1 + (size_t)N * 4;              // N*4
  float* H2 = AD1 + (size_t)N * 4;               // N*64
  float* AS2 = H2 + (size_t)N * 64;              // N*2
  float* AD2 = AS2 + (size_t)N * 2;              // N*2
  float* CS = AD2 + (size_t)N * 2;               // 64 (52 used)
  float* CD = CS + 64;                           // 64
  float* BNS = CD + 64;                          // 256
  float* BNQ = BNS + 256;                        // 256
  int* ROWPTR = (int*)(BNQ + 256);               // N+1
  int* CURS = ROWPTR + (N + 1);                  // N
  int* CSRS = CURS + N;                          // Et
  int* BLKSUM = CSRS + Et;                       // <=1024

  // zero the atomic accumulators (ws is re-poisoned before every launch)
  hipMemsetAsync(CURS, 0, (size_t)N * sizeof(int), stream);
  hipMemsetAsync(BNS, 0, 512 * sizeof(float), stream);

  int eb = (Et + 255) / 256;
  int nbs = (N + 1023) / 1024;
  // CSR build (shared by both layers); hierarchical 3-pass scan
  kc_hist<<<eb, 256, 0, stream>>>(dstp, CURS, E, Et);
  kc_scan1<<<nbs, 1024, 0, stream>>>(CURS, ROWPTR, BLKSUM, N);
  kc_scan2<<<1, 1024, 0, stream>>>(BLKSUM, nbs);
  kc_scan3<<<nbs, 1024, 0, stream>>>(ROWPTR, CURS, BLKSUM, N, Et);
  kc_scatter<<<eb, 256, 0, stream>>>(srcp, dstp, CURS, CSRS, E, Et);

  // layer 1 (h1 never materialized)
  kp_proj<<<1, 64, 0, stream>>>(W1, as1w, ad1w, CS, CD);
  ka_logits<<<(N + 255) / 256, 256, 0, stream>>>(x, CS, CD, AS1, AD1, N);
  agg_x<<<(N + 3) / 4, 256, 0, stream>>>(x, AS1, AD1, ROWPTR, CSRS, Y, N);
  k1b_dense<<<256, 256, 0, stream>>>(Y, W1, O1, BNS, BNQ, N);
  k6_bn_elu<<<4096, 256, 0, stream>>>(O1, BNS, BNQ, gamma1, beta1, N);

  // layer 2
  k7_linear2<<<(N + 3) / 4, 256, 0, stream>>>(O1, W2, as2w, ad2w, H2, AS2, AD2, N);
  kagg2_head<<<(N + 3) / 4, 256, 0, stream>>>(H2, AS2, AD2, ROWPTR, CSRS,
                                              b2, Wc, bc, (float*)d_out, N);
}